// Round 1
// baseline (256.124 us; speedup 1.0000x reference)
//
#include <hip/hip_runtime.h>

#define N_NODE 200
#define T_LEN 360
#define T_POOL 350
#define P_PAT 400
#define P_PAD 512
#define NWIN 14
#define STRIDE_ 25

// ---- workspace layout (bytes) ----
#define O_NPATT 0            // [200][512] f32 = 409600 (zero-padded p>=400)
#define O_MG    409600       // [200][200] i32 = 160000
#define O_TOPN  569600       // [400][3] i32
#define O_TOPV  574464       // [400][3] f32
#define O_COEF  579328       // [400][2] f32
#define O_INVN  582656       // [128][360] f32 = 184320
#define O_POS   766976       // [128][512][14] u32 = 3670016  (total ~4.44 MB)

__device__ __forceinline__ unsigned fkey(float f) {
    unsigned u = __float_as_uint(f);
    return (u & 0x80000000u) ? ~u : (u | 0x80000000u);
}

// ---- pattern prep: row-normalize, top-3 by |value|, norm loss, maskgraph ----
__global__ void k_pat(const float* __restrict__ pat, float* __restrict__ npatT,
                      int* __restrict__ mg, int* __restrict__ topn_w,
                      float* __restrict__ topv_w, float* __restrict__ norm_out)
{
    int p = blockIdx.x;
    int lane = threadIdx.x;
    float sv[4], av[4];
    int nn[4];
    float ss = 0.f;
    #pragma unroll
    for (int j = 0; j < 4; ++j) {
        int n = lane + 64 * j;
        nn[j] = n;
        if (n < N_NODE) { float v = pat[p * N_NODE + n]; sv[j] = v; av[j] = fabsf(v); ss += v * v; }
        else { sv[j] = 0.f; av[j] = -1.f; }
    }
    #pragma unroll
    for (int off = 32; off >= 1; off >>= 1) ss += __shfl_xor(ss, off);
    float rn = 1.0f / sqrtf(ss + 1e-9f);
    #pragma unroll
    for (int j = 0; j < 4; ++j)
        if (nn[j] < N_NODE) npatT[nn[j] * P_PAD + p] = sv[j] * rn;

    int topn[3]; float topv[3];
    for (int r = 0; r < 3; ++r) {
        float bv = -2.f; int bi = 1 << 30;
        #pragma unroll
        for (int j = 0; j < 4; ++j)
            if (av[j] > bv || (av[j] == bv && nn[j] < bi)) { bv = av[j]; bi = nn[j]; }
        #pragma unroll
        for (int off = 32; off >= 1; off >>= 1) {
            float ov = __shfl_xor(bv, off); int oi = __shfl_xor(bi, off);
            if (ov > bv || (ov == bv && oi < bi)) { bv = ov; bi = oi; }
        }
        int jj = bi >> 6, src = bi & 63;
        float rawj = (jj == 0) ? sv[0] : (jj == 1) ? sv[1] : (jj == 2) ? sv[2] : sv[3];
        float raw = __shfl(rawj, src);
        topn[r] = bi; topv[r] = raw * rn;
        #pragma unroll
        for (int j = 0; j < 4; ++j) if (nn[j] == bi) av[j] = -1.f;
    }
    float fullnorm = sqrtf(ss) * rn;
    float topnorm = sqrtf(topv[0]*topv[0] + topv[1]*topv[1] + topv[2]*topv[2]);
    if (lane == 0) {
        float d = 1.0f - topnorm / fullnorm;
        atomicAdd(norm_out, d * d * (1.0f / 800.0f));
    }
    if (lane < 3) { topn_w[p * 3 + lane] = topn[lane]; topv_w[p * 3 + lane] = topv[lane]; }
    if (lane < 9) {
        int i = lane / 3, j = lane % 3;
        atomicAdd(&mg[topn[i] * N_NODE + topn[j]], 1);
    }
}

// ---- fold sparse graph + classifier into per-pattern coefficients ----
__global__ void k_coef(const int* __restrict__ topn_w, const float* __restrict__ topv_w,
                       const int* __restrict__ mg, const float* __restrict__ W,
                       float* __restrict__ coef)
{
    int p = blockIdx.x * blockDim.x + threadIdx.x;
    if (p >= P_PAT) return;
    int tn[3]; float tv[3];
    #pragma unroll
    for (int i = 0; i < 3; ++i) { tn[i] = topn_w[p * 3 + i]; tv[i] = topv_w[p * 3 + i]; }
    float c0 = 0.f, c1 = 0.f;
    #pragma unroll
    for (int i = 0; i < 3; ++i)
        #pragma unroll
        for (int j = 0; j < 3; ++j) {
            int nm = tn[i] * N_NODE + tn[j];
            float f = tv[i] * tv[j] / ((float)mg[nm] + 1e-9f);
            c0 += f * W[nm * 2 + 0];
            c1 += f * W[nm * 2 + 1];
        }
    coef[p * 2 + 0] = c0; coef[p * 2 + 1] = c1;
}

// ---- per-(b,t) inverse frame norm, with validity mask and 1/sap folded in ----
__global__ void k_invn(const float* __restrict__ x, const int* __restrict__ length,
                       float* __restrict__ invn)
{
    int b = blockIdx.y;
    int t = blockIdx.x * 180 + threadIdx.x;
    if (threadIdx.x >= 180) return;
    const float* xb = x + (size_t)b * N_NODE * T_LEN;
    float ss = 0.f;
    for (int n = 0; n < N_NODE; ++n) { float v = xb[n * T_LEN + t]; ss += v * v; }
    int sap = length[b] / STRIDE_;
    float iv = (t < sap * STRIDE_) ? (1.0f / (sqrtf(ss + 1e-9f) * (float)sap)) : 0.0f;
    invn[b * T_LEN + t] = iv;
}

// ---- batched GEMM (npat @ x_b) + column scale + windowed max into atomic keys ----
__global__ __launch_bounds__(256) void k_gemm(const float* __restrict__ x,
    const float* __restrict__ npatT, const float* __restrict__ invn,
    unsigned* __restrict__ pos)
{
    __shared__ float As[8][128];
    __shared__ float Xs[8][128];
    __shared__ float Ss[16][132];   // +4 pad breaks p-stride bank aliasing in pool pass
    int tid = threadIdx.x;
    int b  = blockIdx.z;
    int p0 = blockIdx.y * 128;
    int t0 = blockIdx.x * 128;
    int tp = tid >> 4, tt = tid & 15;
    int lk = tid >> 5;              // 0..7  (k row within chunk)
    int lo = (tid & 31) * 4;        // 0..124 (float4 column)
    const float* xb = x + (size_t)b * N_NODE * T_LEN;

    float acc[8][8];
    #pragma unroll
    for (int i = 0; i < 8; ++i)
        #pragma unroll
        for (int j = 0; j < 8; ++j) acc[i][j] = 0.f;

    float4 aR = *(const float4*)(npatT + lk * P_PAD + p0 + lo);
    float4 xR;
    {
        int t = t0 + lo;
        xR = (t < T_LEN) ? *(const float4*)(xb + lk * T_LEN + t) : make_float4(0.f, 0.f, 0.f, 0.f);
    }
    for (int it = 0; it < 25; ++it) {
        __syncthreads();
        *(float4*)&As[lk][lo] = aR;
        *(float4*)&Xs[lk][lo] = xR;
        __syncthreads();
        if (it < 24) {
            int k0 = (it + 1) * 8;
            aR = *(const float4*)(npatT + (k0 + lk) * P_PAD + p0 + lo);
            int t = t0 + lo;
            xR = (t < T_LEN) ? *(const float4*)(xb + (k0 + lk) * T_LEN + t)
                             : make_float4(0.f, 0.f, 0.f, 0.f);
        }
        #pragma unroll
        for (int k = 0; k < 8; ++k) {
            float a[8], xv[8];
            *(float4*)&a[0]  = *(const float4*)&As[k][tp * 8];
            *(float4*)&a[4]  = *(const float4*)&As[k][tp * 8 + 4];
            *(float4*)&xv[0] = *(const float4*)&Xs[k][tt * 8];
            *(float4*)&xv[4] = *(const float4*)&Xs[k][tt * 8 + 4];
            #pragma unroll
            for (int i = 0; i < 8; ++i)
                #pragma unroll
                for (int j = 0; j < 8; ++j)
                    acc[i][j] = fmaf(a[i], xv[j], acc[i][j]);
        }
    }

    float inv[8];
    #pragma unroll
    for (int j = 0; j < 8; ++j) {
        int t = t0 + tt * 8 + j;
        inv[j] = (t < T_LEN) ? invn[b * T_LEN + t] : 0.f;
    }
    int wbase = t0 / STRIDE_;
    int tmax = min(t0 + 128, T_POOL);
    for (int r = 0; r < 8; ++r) {
        __syncthreads();
        float4 w0, w1;
        w0.x = acc[r][0] * inv[0]; w0.y = acc[r][1] * inv[1];
        w0.z = acc[r][2] * inv[2]; w0.w = acc[r][3] * inv[3];
        w1.x = acc[r][4] * inv[4]; w1.y = acc[r][5] * inv[5];
        w1.z = acc[r][6] * inv[6]; w1.w = acc[r][7] * inv[7];
        *(float4*)&Ss[tp][tt * 8]     = w0;
        *(float4*)&Ss[tp][tt * 8 + 4] = w1;
        __syncthreads();
        if (tid < 128) {
            int s = tid & 7, pl = tid >> 3;
            int w = wbase + s;
            int tlo = max(w * STRIDE_, t0);
            int thi = min(w * STRIDE_ + STRIDE_, tmax);
            if (w < NWIN && tlo < thi) {
                float m = -3.4e38f;
                for (int t = tlo; t < thi; ++t) m = fmaxf(m, Ss[pl][t - t0]);
                atomicMax(&pos[((size_t)b * P_PAD + p0 + pl * 8 + r) * NWIN + w], fkey(m));
            }
        }
    }
}

// ---- final: fs[b,p] = sum_w unmap(pos); out = fs @ coef + b_cls ----
__global__ void k_out(const unsigned* __restrict__ pos, const float* __restrict__ coef,
                      const float* __restrict__ bcls, float* __restrict__ out)
{
    int b = blockIdx.x, tid = threadIdx.x;
    float s0 = 0.f, s1 = 0.f;
    for (int p = tid; p < P_PAT; p += 256) {
        const unsigned* pp = pos + ((size_t)b * P_PAD + p) * NWIN;
        float fs = 0.f;
        #pragma unroll
        for (int w = 0; w < NWIN; ++w) {
            unsigned k = pp[w];
            unsigned u = (k & 0x80000000u) ? (k ^ 0x80000000u) : ~k;
            fs += __uint_as_float(u);
        }
        s0 += fs * coef[p * 2 + 0];
        s1 += fs * coef[p * 2 + 1];
    }
    __shared__ float sh[512];
    sh[tid] = s0; sh[256 + tid] = s1;
    __syncthreads();
    for (int o = 128; o > 0; o >>= 1) {
        if (tid < o) { sh[tid] += sh[tid + o]; sh[256 + tid] += sh[256 + tid + o]; }
        __syncthreads();
    }
    if (tid == 0) {
        out[b * 2 + 0] = sh[0]   + bcls[0];
        out[b * 2 + 1] = sh[256] + bcls[1];
    }
}

extern "C" void kernel_launch(void* const* d_in, const int* in_sizes, int n_in,
                              void* d_out, int out_size, void* d_ws, size_t ws_size,
                              hipStream_t stream) {
    (void)in_sizes; (void)n_in; (void)out_size; (void)ws_size;
    const float* x        = (const float*)d_in[0];
    const int*   length   = (const int*)d_in[1];
    const float* patterns = (const float*)d_in[2];
    const float* Wcls     = (const float*)d_in[3];
    const float* bcls     = (const float*)d_in[4];
    float* out = (float*)d_out;
    char* ws = (char*)d_ws;

    float*    npatT = (float*)(ws + O_NPATT);
    int*      mg    = (int*)(ws + O_MG);
    int*      topn  = (int*)(ws + O_TOPN);
    float*    topv  = (float*)(ws + O_TOPV);
    float*    coef  = (float*)(ws + O_COEF);
    float*    invn  = (float*)(ws + O_INVN);
    unsigned* pos   = (unsigned*)(ws + O_POS);

    // zero: npatT (incl. p>=400 padding) + mg are contiguous; pos keys; norm+rec outputs
    hipMemsetAsync(ws, 0, O_MG + 160000, stream);
    hipMemsetAsync(pos, 0, (size_t)128 * P_PAD * NWIN * 4, stream);
    hipMemsetAsync((char*)d_out + 256 * 4, 0, 8, stream);

    k_pat<<<P_PAT, 64, 0, stream>>>(patterns, npatT, mg, topn, topv, out + 256);
    k_coef<<<2, 256, 0, stream>>>(topn, topv, mg, Wcls, coef);
    k_invn<<<dim3(2, 128), 192, 0, stream>>>(x, length, invn);
    k_gemm<<<dim3(3, 4, 128), 256, 0, stream>>>(x, npatT, invn, pos);
    k_out<<<128, 256, 0, stream>>>(pos, coef, bcls, out);
}

// Round 2
// 231.718 us; speedup vs baseline: 1.1053x; 1.1053x over previous
//
#include <hip/hip_runtime.h>

#define N_NODE 200
#define T_LEN 360
#define T_POOL 350
#define P_PAT 400
#define P_PAD 512
#define NWIN 14
#define STRIDE_ 25

// ---- workspace layout (bytes); [0, O_TOPN) is zeroed with ONE memset ----
#define O_NPATT 0            // [200][512] f32 = 409600 (zero-padded p>=400)
#define O_MG    409600       // [200][200] i32 = 160000
#define O_POS   569600       // [128][512][14] u32 = 3670016
#define O_TOPN  4239616      // [400][3] i32
#define O_TOPV  4244416      // [400][3] f32
#define O_NORMT 4249216      // [400] f32
#define ZERO_BYTES 4239616

__device__ __forceinline__ unsigned fkey(float f) {
    unsigned u = __float_as_uint(f);
    return (u & 0x80000000u) ? ~u : (u | 0x80000000u);
}

// ---- pattern prep: row-normalize, top-3 by |value|, per-p norm term, maskgraph ----
__global__ void k_pat(const float* __restrict__ pat, float* __restrict__ npatT,
                      int* __restrict__ mg, int* __restrict__ topn_w,
                      float* __restrict__ topv_w, float* __restrict__ normt)
{
    int p = blockIdx.x;
    int lane = threadIdx.x;
    float sv[4], av[4];
    int nn[4];
    float ss = 0.f;
    #pragma unroll
    for (int j = 0; j < 4; ++j) {
        int n = lane + 64 * j;
        nn[j] = n;
        if (n < N_NODE) { float v = pat[p * N_NODE + n]; sv[j] = v; av[j] = fabsf(v); ss += v * v; }
        else { sv[j] = 0.f; av[j] = -1.f; }
    }
    #pragma unroll
    for (int off = 32; off >= 1; off >>= 1) ss += __shfl_xor(ss, off);
    float rn = 1.0f / sqrtf(ss + 1e-9f);
    #pragma unroll
    for (int j = 0; j < 4; ++j)
        if (nn[j] < N_NODE) npatT[nn[j] * P_PAD + p] = sv[j] * rn;

    int topn[3]; float topv[3];
    for (int r = 0; r < 3; ++r) {
        float bv = -2.f; int bi = 1 << 30;
        #pragma unroll
        for (int j = 0; j < 4; ++j)
            if (av[j] > bv || (av[j] == bv && nn[j] < bi)) { bv = av[j]; bi = nn[j]; }
        #pragma unroll
        for (int off = 32; off >= 1; off >>= 1) {
            float ov = __shfl_xor(bv, off); int oi = __shfl_xor(bi, off);
            if (ov > bv || (ov == bv && oi < bi)) { bv = ov; bi = oi; }
        }
        int jj = bi >> 6, src = bi & 63;
        float rawj = (jj == 0) ? sv[0] : (jj == 1) ? sv[1] : (jj == 2) ? sv[2] : sv[3];
        float raw = __shfl(rawj, src);
        topn[r] = bi; topv[r] = raw * rn;
        #pragma unroll
        for (int j = 0; j < 4; ++j) if (nn[j] == bi) av[j] = -1.f;
    }
    float fullnorm = sqrtf(ss) * rn;
    float topnorm = sqrtf(topv[0]*topv[0] + topv[1]*topv[1] + topv[2]*topv[2]);
    if (lane == 0) {
        float d = 1.0f - topnorm / fullnorm;
        normt[p] = d * d * (1.0f / 800.0f);
    }
    if (lane < 3) { topn_w[p * 3 + lane] = topn[lane]; topv_w[p * 3 + lane] = topv[lane]; }
    if (lane < 9) {
        int i = lane / 3, j = lane % 3;
        atomicAdd(&mg[topn[i] * N_NODE + topn[j]], 1);
    }
}

// ---- batched GEMM (npat @ x_b) + inline frame-norm + windowed max into atomic keys ----
// thread (tp,tt): p rows {tp*8+i}, t cols {tt*4+j, 64+tt*4+j}  (j-split kills 4-way LDS conflicts)
__global__ __launch_bounds__(256) void k_gemm(const float* __restrict__ x,
    const float* __restrict__ npatT, const int* __restrict__ length,
    unsigned* __restrict__ pos)
{
    __shared__ float smem[2112];          // As=[0,1024) [8][128]; Xs=[1024,2048); Ss aliases [16][132]
    float* As = smem;
    float* Xs = smem + 1024;
    int tid = threadIdx.x;
    int b  = blockIdx.z;
    int p0 = blockIdx.y * 128;
    int t0 = blockIdx.x * 128;
    int tp = tid >> 4, tt = tid & 15;
    int lk = tid >> 5;                    // 0..7
    int lo = (tid & 31) * 4;              // 0..124
    const float* xb = x + (size_t)b * (N_NODE * T_LEN);

    float acc[8][8];
    float ssq[8];
    #pragma unroll
    for (int i = 0; i < 8; ++i) {
        ssq[i] = 0.f;
        #pragma unroll
        for (int j = 0; j < 8; ++j) acc[i][j] = 0.f;
    }

    float4 aR = *(const float4*)(npatT + lk * P_PAD + p0 + lo);
    float4 xR;
    {
        int t = t0 + lo;
        xR = (t < T_LEN) ? *(const float4*)(xb + lk * T_LEN + t) : make_float4(0.f, 0.f, 0.f, 0.f);
    }
    for (int it = 0; it < 25; ++it) {
        __syncthreads();
        *(float4*)&As[lk * 128 + lo] = aR;
        *(float4*)&Xs[lk * 128 + lo] = xR;
        __syncthreads();
        if (it < 24) {
            int k0 = (it + 1) * 8;
            aR = *(const float4*)(npatT + (k0 + lk) * P_PAD + p0 + lo);
            int t = t0 + lo;
            xR = (t < T_LEN) ? *(const float4*)(xb + (k0 + lk) * T_LEN + t)
                             : make_float4(0.f, 0.f, 0.f, 0.f);
        }
        #pragma unroll
        for (int k = 0; k < 8; ++k) {
            float a[8], xv[8];
            *(float4*)&a[0]  = *(const float4*)&As[k * 128 + tp * 8];
            *(float4*)&a[4]  = *(const float4*)&As[k * 128 + tp * 8 + 4];
            *(float4*)&xv[0] = *(const float4*)&Xs[k * 128 + tt * 4];        // 2-way alias: free
            *(float4*)&xv[4] = *(const float4*)&Xs[k * 128 + 64 + tt * 4];   // 2-way alias: free
            #pragma unroll
            for (int j = 0; j < 8; ++j) ssq[j] = fmaf(xv[j], xv[j], ssq[j]);
            #pragma unroll
            for (int i = 0; i < 8; ++i)
                #pragma unroll
                for (int j = 0; j < 8; ++j)
                    acc[i][j] = fmaf(a[i], xv[j], acc[i][j]);
        }
    }

    // inline invn: ssq[j] is the full sum over k=0..199 for this thread's column j
    int sap = length[b] / STRIDE_;
    int tvalid = sap * STRIDE_;           // <= 350 < 360, so t>=360 garbage-free
    float inv[8];
    #pragma unroll
    for (int j = 0; j < 8; ++j) {
        int t = t0 + ((j < 4) ? (tt * 4 + j) : (64 + tt * 4 + (j - 4)));
        float iv = 1.0f / (sqrtf(ssq[j] + 1e-9f) * (float)sap);
        inv[j] = (t < tvalid) ? iv : 0.f;
    }

    float* Ss = smem;                     // [16][132], aliases As/Xs (dead after k-loop)
    int wbase = t0 / STRIDE_;
    int tmax = min(t0 + 128, T_POOL);
    for (int r = 0; r < 8; ++r) {
        __syncthreads();
        float4 w0, w1;
        w0.x = acc[r][0] * inv[0]; w0.y = acc[r][1] * inv[1];
        w0.z = acc[r][2] * inv[2]; w0.w = acc[r][3] * inv[3];
        w1.x = acc[r][4] * inv[4]; w1.y = acc[r][5] * inv[5];
        w1.z = acc[r][6] * inv[6]; w1.w = acc[r][7] * inv[7];
        *(float4*)&Ss[tp * 132 + tt * 4]      = w0;
        *(float4*)&Ss[tp * 132 + 64 + tt * 4] = w1;
        __syncthreads();
        if (tid < 128) {
            int s = tid & 7, pl = tid >> 3;
            int w = wbase + s;
            int tlo = max(w * STRIDE_, t0);
            int thi = min(w * STRIDE_ + STRIDE_, tmax);
            if (w < NWIN && tlo < thi) {
                float m = -3.4e38f;
                for (int t = tlo; t < thi; ++t) m = fmaxf(m, Ss[pl * 132 + (t - t0)]);
                atomicMax(&pos[((size_t)b * P_PAD + p0 + pl * 8 + r) * NWIN + w], fkey(m));
            }
        }
    }
}

// ---- final: coef inline (sparse graph x classifier), fs reduce, norm reduce (block 0) ----
__global__ void k_out(const unsigned* __restrict__ pos, const int* __restrict__ topn_w,
                      const float* __restrict__ topv_w, const int* __restrict__ mg,
                      const float* __restrict__ W, const float* __restrict__ normt,
                      const float* __restrict__ bcls, float* __restrict__ out)
{
    __shared__ float cf0[P_PAT], cf1[P_PAT];
    __shared__ float sh[512];
    int b = blockIdx.x, tid = threadIdx.x;
    for (int p = tid; p < P_PAT; p += 256) {
        int tn[3]; float tv[3];
        #pragma unroll
        for (int i = 0; i < 3; ++i) { tn[i] = topn_w[p * 3 + i]; tv[i] = topv_w[p * 3 + i]; }
        float c0 = 0.f, c1 = 0.f;
        #pragma unroll
        for (int i = 0; i < 3; ++i)
            #pragma unroll
            for (int j = 0; j < 3; ++j) {
                int nm = tn[i] * N_NODE + tn[j];
                float f = tv[i] * tv[j] / ((float)mg[nm] + 1e-9f);
                c0 += f * W[nm * 2 + 0];
                c1 += f * W[nm * 2 + 1];
            }
        cf0[p] = c0; cf1[p] = c1;
    }
    __syncthreads();
    float s0 = 0.f, s1 = 0.f;
    for (int p = tid; p < P_PAT; p += 256) {
        const unsigned* pp = pos + ((size_t)b * P_PAD + p) * NWIN;
        float fs = 0.f;
        #pragma unroll
        for (int w = 0; w < NWIN; ++w) {
            unsigned k = pp[w];
            unsigned u = (k & 0x80000000u) ? (k ^ 0x80000000u) : ~k;
            fs += __uint_as_float(u);
        }
        s0 += fs * cf0[p];
        s1 += fs * cf1[p];
    }
    sh[tid] = s0; sh[256 + tid] = s1;
    __syncthreads();
    for (int o = 128; o > 0; o >>= 1) {
        if (tid < o) { sh[tid] += sh[tid + o]; sh[256 + tid] += sh[256 + tid + o]; }
        __syncthreads();
    }
    if (tid == 0) {
        out[b * 2 + 0] = sh[0]   + bcls[0];
        out[b * 2 + 1] = sh[256] + bcls[1];
    }
    if (b == 0) {   // block-uniform branch: barriers inside are legal
        __syncthreads();
        float ns = 0.f;
        for (int i = tid; i < P_PAT; i += 256) ns += normt[i];
        sh[tid] = ns;
        __syncthreads();
        for (int o = 128; o > 0; o >>= 1) {
            if (tid < o) sh[tid] += sh[tid + o];
            __syncthreads();
        }
        if (tid == 0) { out[256] = sh[0]; out[257] = 0.f; }
    }
}

extern "C" void kernel_launch(void* const* d_in, const int* in_sizes, int n_in,
                              void* d_out, int out_size, void* d_ws, size_t ws_size,
                              hipStream_t stream) {
    (void)in_sizes; (void)n_in; (void)out_size; (void)ws_size;
    const float* x        = (const float*)d_in[0];
    const int*   length   = (const int*)d_in[1];
    const float* patterns = (const float*)d_in[2];
    const float* Wcls     = (const float*)d_in[3];
    const float* bcls     = (const float*)d_in[4];
    float* out = (float*)d_out;
    char* ws = (char*)d_ws;

    float*    npatT = (float*)(ws + O_NPATT);
    int*      mg    = (int*)(ws + O_MG);
    unsigned* pos   = (unsigned*)(ws + O_POS);
    int*      topn  = (int*)(ws + O_TOPN);
    float*    topv  = (float*)(ws + O_TOPV);
    float*    normt = (float*)(ws + O_NORMT);

    hipMemsetAsync(ws, 0, ZERO_BYTES, stream);                    // npatT + mg + pos in one node
    k_pat<<<P_PAT, 64, 0, stream>>>(patterns, npatT, mg, topn, topv, normt);
    k_gemm<<<dim3(3, 4, 128), 256, 0, stream>>>(x, npatT, length, pos);
    k_out<<<128, 256, 0, stream>>>(pos, topn, topv, mg, Wcls, normt, bcls, out);
}

// Round 3
// 188.093 us; speedup vs baseline: 1.3617x; 1.2319x over previous
//
#include <hip/hip_runtime.h>

#define N_NODE 200
#define T_LEN 360
#define T_POOL 350
#define P_PAT 400
#define P_PAD 512
#define NWIN 14
#define STRIDE_ 25
#define KPAD 224            // 7 stages x 32

// ---- workspace layout (bytes) ----
#define O_AH    0           // [7][512][32] bf16 = 229376   (pattern hi, stage-major)
#define O_AL    229376      // [7][512][32] bf16 = 229376   (pattern lo)
#define O_MG    458752      // [200][200] i32 = 160000      (memset 0)
#define O_POS   618752      // [128][512][14] u32 = 3670016 (zeroed by k_pat)
#define O_TOPN  4288768     // [400][3] i32
#define O_TOPV  4293568     // [400][3] f32
#define O_NORMT 4298368     // [400] f32

typedef unsigned short u16;
typedef __attribute__((ext_vector_type(8))) short bf16x8;
typedef __attribute__((ext_vector_type(4))) float f32x4;

__device__ __forceinline__ unsigned fkey(float f) {
    unsigned u = __float_as_uint(f);
    return (u & 0x80000000u) ? ~u : (u | 0x80000000u);
}
__device__ __forceinline__ u16 f2bf(float f) {          // RNE truncate f32->bf16
    unsigned u = __float_as_uint(f);
    unsigned r = u + 0x7FFFu + ((u >> 16) & 1u);
    return (u16)(r >> 16);
}
__device__ __forceinline__ float bf2f(u16 h) { return __uint_as_float(((unsigned)h) << 16); }

// ---- pattern prep: normalize, top-3, norm term, maskgraph, bf16 hi/lo split, pos zero ----
__global__ void k_pat(const float* __restrict__ pat, u16* __restrict__ Ah, u16* __restrict__ Al,
                      int* __restrict__ mg, int* __restrict__ topn_w,
                      float* __restrict__ topv_w, float* __restrict__ normt,
                      unsigned* __restrict__ pos)
{
    int p = blockIdx.x;               // 0..511
    int lane = threadIdx.x;
    bool pv = p < P_PAT;

    // zero pos: 917504 u32 over 512 blocks x 64 threads = 28 each
    {
        int base = blockIdx.x * 64 + lane;
        #pragma unroll
        for (int i = 0; i < 28; ++i) pos[base + i * 32768] = 0u;
    }

    float sv[4], av[4];
    int nn[4];
    float ss = 0.f;
    #pragma unroll
    for (int j = 0; j < 4; ++j) {
        int n = lane + 64 * j;
        nn[j] = n;
        if (pv && n < N_NODE) { float v = pat[p * N_NODE + n]; sv[j] = v; av[j] = fabsf(v); ss += v * v; }
        else { sv[j] = 0.f; av[j] = -1.f; }
    }
    #pragma unroll
    for (int off = 32; off >= 1; off >>= 1) ss += __shfl_xor(ss, off);
    float rn = 1.0f / sqrtf(ss + 1e-9f);

    // split write: [s][p][32k], all 224 slots covered (zeros for pads)
    #pragma unroll
    for (int j = 0; j < 4; ++j) {
        int n = nn[j];
        if (n < KPAD) {
            float v = (pv && n < N_NODE) ? sv[j] * rn : 0.f;
            u16 h = f2bf(v);
            u16 l = f2bf(v - bf2f(h));
            size_t idx = (size_t)(n >> 5) * (P_PAD * 32) + (size_t)p * 32 + (n & 31);
            Ah[idx] = h; Al[idx] = l;
        }
    }
    if (!pv) return;

    int topn[3]; float topv[3];
    for (int r = 0; r < 3; ++r) {
        float bv = -2.f; int bi = 1 << 30;
        #pragma unroll
        for (int j = 0; j < 4; ++j)
            if (av[j] > bv || (av[j] == bv && nn[j] < bi)) { bv = av[j]; bi = nn[j]; }
        #pragma unroll
        for (int off = 32; off >= 1; off >>= 1) {
            float ov = __shfl_xor(bv, off); int oi = __shfl_xor(bi, off);
            if (ov > bv || (ov == bv && oi < bi)) { bv = ov; bi = oi; }
        }
        int jj = bi >> 6, src = bi & 63;
        float rawj = (jj == 0) ? sv[0] : (jj == 1) ? sv[1] : (jj == 2) ? sv[2] : sv[3];
        float raw = __shfl(rawj, src);
        topn[r] = bi; topv[r] = raw * rn;
        #pragma unroll
        for (int j = 0; j < 4; ++j) if (nn[j] == bi) av[j] = -1.f;
    }
    float fullnorm = sqrtf(ss) * rn;
    float topnorm = sqrtf(topv[0]*topv[0] + topv[1]*topv[1] + topv[2]*topv[2]);
    if (lane == 0) {
        float d = 1.0f - topnorm / fullnorm;
        normt[p] = d * d * (1.0f / 800.0f);
    }
    if (lane < 3) { topn_w[p * 3 + lane] = topn[lane]; topv_w[p * 3 + lane] = topv[lane]; }
    if (lane < 9) {
        int i = lane / 3, j = lane % 3;
        atomicAdd(&mg[topn[i] * N_NODE + topn[j]], 1);
    }
}

// ---- MFMA GEMM (bf16x3 split) + inline frame-norm + windowed max ----
// block 256 thr = 4 waves (2x2), block tile p128 x t128, wave tile 64x64 = 4x4 of 16x16x32
#define LDS_AH 0
#define LDS_AL 8192
#define LDS_XH 16384
#define LDS_XL 24576
#define LDS_SS 0          // alias over As (dead after K-loop): 16*132*4 = 8448
#define LDS_SQ 8704       // 256*4
#define LDS_IV 9728       // 128*4
__global__ __launch_bounds__(256, 2) void k_gemm(const float* __restrict__ x,
    const u16* __restrict__ Ah, const u16* __restrict__ Al,
    const int* __restrict__ length, unsigned* __restrict__ pos)
{
    __shared__ __align__(16) char smem[32768];
    int tid = threadIdx.x;
    int b = blockIdx.z, p0 = blockIdx.y * 128, t0 = blockIdx.x * 128;
    int lane = tid & 63, wid = tid >> 6;
    int quad = lane >> 4, lm = lane & 15;
    int wp = wid >> 1, wt = wid & 1;
    const float* xb = x + (size_t)b * (N_NODE * T_LEN);

    f32x4 acc[4][4];
    #pragma unroll
    for (int i = 0; i < 4; ++i)
        #pragma unroll
        for (int j = 0; j < 4; ++j) acc[i][j] = (f32x4){0.f, 0.f, 0.f, 0.f};
    float ssq = 0.f;

    int st = tid & 127, kh = tid >> 7;           // staging coords: t-col, k-half
    int tg = t0 + st;
    bool tok = tg < T_LEN;
    int pbase = wid * 32;

    uint4 pa_h[2], pa_l[2];
    float xv[16];

    auto loadA = [&](int s) {
        const u16* g  = Ah + (size_t)(s * P_PAD + p0 + pbase) * 32 + lane * 8;
        const u16* g2 = Al + (size_t)(s * P_PAD + p0 + pbase) * 32 + lane * 8;
        pa_h[0] = *(const uint4*)g;   pa_h[1] = *(const uint4*)(g + 512);
        pa_l[0] = *(const uint4*)g2;  pa_l[1] = *(const uint4*)(g2 + 512);
    };
    auto loadX = [&](int s) {
        int kb = s * 32 + kh * 16;
        #pragma unroll
        for (int j = 0; j < 16; ++j) {
            int k = kb + j;
            xv[j] = (tok && k < N_NODE) ? xb[k * T_LEN + tg] : 0.f;
        }
    };

    loadA(0); loadX(0);
    for (int s = 0; s < 7; ++s) {
        __syncthreads();
        // stage A (pre-split bf16, linear conflict-free writes)
        *(uint4*)&smem[LDS_AH + pbase * 64 + lane * 16]        = pa_h[0];
        *(uint4*)&smem[LDS_AH + (pbase + 16) * 64 + lane * 16] = pa_h[1];
        *(uint4*)&smem[LDS_AL + pbase * 64 + lane * 16]        = pa_l[0];
        *(uint4*)&smem[LDS_AL + (pbase + 16) * 64 + lane * 16] = pa_l[1];
        // stage X: convert f32 -> hi/lo bf16, accumulate ssq
        #pragma unroll
        for (int g = 0; g < 2; ++g) {
            int kg = kh * 2 + g;
            union { u16 us[8]; uint4 v; } H, L;
            #pragma unroll
            for (int j = 0; j < 8; ++j) {
                float f = xv[g * 8 + j];
                ssq = fmaf(f, f, ssq);
                u16 h = f2bf(f);
                H.us[j] = h;
                L.us[j] = f2bf(f - bf2f(h));
            }
            *(uint4*)&smem[LDS_XH + (kg * 128 + st) * 16] = H.v;
            *(uint4*)&smem[LDS_XL + (kg * 128 + st) * 16] = L.v;
        }
        __syncthreads();
        if (s < 6) { loadA(s + 1); loadX(s + 1); }   // global prefetch overlaps MFMA
        bf16x8 ah[4], al[4], xh[4], xl[4];
        #pragma unroll
        for (int i = 0; i < 4; ++i) {
            int prow = wp * 64 + i * 16 + lm;
            int tcol = wt * 64 + i * 16 + lm;
            ah[i] = *(bf16x8*)&smem[LDS_AH + (prow * 4 + quad) * 16];
            al[i] = *(bf16x8*)&smem[LDS_AL + (prow * 4 + quad) * 16];
            xh[i] = *(bf16x8*)&smem[LDS_XH + (quad * 128 + tcol) * 16];
            xl[i] = *(bf16x8*)&smem[LDS_XL + (quad * 128 + tcol) * 16];
        }
        #pragma unroll
        for (int i = 0; i < 4; ++i)
            #pragma unroll
            for (int j = 0; j < 4; ++j) {
                acc[i][j] = __builtin_amdgcn_mfma_f32_16x16x32_bf16(ah[i], xh[j], acc[i][j], 0, 0, 0);
                acc[i][j] = __builtin_amdgcn_mfma_f32_16x16x32_bf16(ah[i], xl[j], acc[i][j], 0, 0, 0);
                acc[i][j] = __builtin_amdgcn_mfma_f32_16x16x32_bf16(al[i], xh[j], acc[i][j], 0, 0, 0);
            }
    }

    // frame-norm: reduce ssq halves, build inv[t] (validity + 1/sap folded)
    __syncthreads();
    *(float*)&smem[LDS_SQ + tid * 4] = ssq;
    __syncthreads();
    int sap = length[b] / STRIDE_;
    int tvalid = sap * STRIDE_;
    if (tid < 128) {
        float tot = *(float*)&smem[LDS_SQ + tid * 4] + *(float*)&smem[LDS_SQ + (128 + tid) * 4];
        float iv = 1.0f / (sqrtf(tot + 1e-9f) * (float)sap);
        *(float*)&smem[LDS_IV + tid * 4] = (t0 + tid < tvalid) ? iv : 0.f;
    }
    __syncthreads();
    float invv[4];
    #pragma unroll
    for (int j = 0; j < 4; ++j) invv[j] = *(float*)&smem[LDS_IV + (wt * 64 + j * 16 + lm) * 4];

    int wbase = t0 / STRIDE_;
    int tmax = min(t0 + 128, T_POOL);
    for (int rr = 0; rr < 8; ++rr) {              // p-slice of 16 rows per round
        __syncthreads();
        if (wp == (rr >> 2)) {
            int pt = rr & 3;
            #pragma unroll
            for (int j = 0; j < 4; ++j)
                #pragma unroll
                for (int r = 0; r < 4; ++r) {
                    float v = acc[pt][j][r] * invv[j];
                    *(float*)&smem[LDS_SS + ((quad * 4 + r) * 132 + wt * 64 + j * 16 + lm) * 4] = v;
                }
        }
        __syncthreads();
        if (tid < 128) {
            int sidx = tid & 7, pl = tid >> 3;
            int w = wbase + sidx;
            int tlo = max(w * STRIDE_, t0), thi = min(w * STRIDE_ + STRIDE_, tmax);
            if (w < NWIN && tlo < thi) {
                float m = -3.4e38f;
                for (int t = tlo; t < thi; ++t)
                    m = fmaxf(m, *(float*)&smem[LDS_SS + (pl * 132 + (t - t0)) * 4]);
                atomicMax(&pos[((size_t)b * P_PAD + p0 + rr * 16 + pl) * NWIN + w], fkey(m));
            }
        }
    }
}

// ---- final: coef inline (sparse graph x classifier), fs reduce, norm reduce ----
__global__ void k_out(const unsigned* __restrict__ pos, const int* __restrict__ topn_w,
                      const float* __restrict__ topv_w, const int* __restrict__ mg,
                      const float* __restrict__ W, const float* __restrict__ normt,
                      const float* __restrict__ bcls, float* __restrict__ out)
{
    __shared__ float cf0[P_PAT], cf1[P_PAT];
    __shared__ float sh[512];
    int b = blockIdx.x, tid = threadIdx.x;
    for (int p = tid; p < P_PAT; p += 256) {
        int tn[3]; float tv[3];
        #pragma unroll
        for (int i = 0; i < 3; ++i) { tn[i] = topn_w[p * 3 + i]; tv[i] = topv_w[p * 3 + i]; }
        float c0 = 0.f, c1 = 0.f;
        #pragma unroll
        for (int i = 0; i < 3; ++i)
            #pragma unroll
            for (int j = 0; j < 3; ++j) {
                int nm = tn[i] * N_NODE + tn[j];
                float f = tv[i] * tv[j] / ((float)mg[nm] + 1e-9f);
                c0 += f * W[nm * 2 + 0];
                c1 += f * W[nm * 2 + 1];
            }
        cf0[p] = c0; cf1[p] = c1;
    }
    __syncthreads();
    float s0 = 0.f, s1 = 0.f;
    for (int p = tid; p < P_PAT; p += 256) {
        const unsigned* pp = pos + ((size_t)b * P_PAD + p) * NWIN;
        float fs = 0.f;
        #pragma unroll
        for (int w = 0; w < NWIN; ++w) {
            unsigned k = pp[w];
            unsigned u = (k & 0x80000000u) ? (k ^ 0x80000000u) : ~k;
            fs += __uint_as_float(u);
        }
        s0 += fs * cf0[p];
        s1 += fs * cf1[p];
    }
    sh[tid] = s0; sh[256 + tid] = s1;
    __syncthreads();
    for (int o = 128; o > 0; o >>= 1) {
        if (tid < o) { sh[tid] += sh[tid + o]; sh[256 + tid] += sh[256 + tid + o]; }
        __syncthreads();
    }
    if (tid == 0) {
        out[b * 2 + 0] = sh[0]   + bcls[0];
        out[b * 2 + 1] = sh[256] + bcls[1];
    }
    if (b == 0) {
        __syncthreads();
        float ns = 0.f;
        for (int i = tid; i < P_PAT; i += 256) ns += normt[i];
        sh[tid] = ns;
        __syncthreads();
        for (int o = 128; o > 0; o >>= 1) {
            if (tid < o) sh[tid] += sh[tid + o];
            __syncthreads();
        }
        if (tid == 0) { out[256] = sh[0]; out[257] = 0.f; }
    }
}

extern "C" void kernel_launch(void* const* d_in, const int* in_sizes, int n_in,
                              void* d_out, int out_size, void* d_ws, size_t ws_size,
                              hipStream_t stream) {
    (void)in_sizes; (void)n_in; (void)out_size; (void)ws_size;
    const float* x        = (const float*)d_in[0];
    const int*   length   = (const int*)d_in[1];
    const float* patterns = (const float*)d_in[2];
    const float* Wcls     = (const float*)d_in[3];
    const float* bcls     = (const float*)d_in[4];
    float* out = (float*)d_out;
    char* ws = (char*)d_ws;

    u16*      Ah    = (u16*)(ws + O_AH);
    u16*      Al    = (u16*)(ws + O_AL);
    int*      mg    = (int*)(ws + O_MG);
    unsigned* pos   = (unsigned*)(ws + O_POS);
    int*      topn  = (int*)(ws + O_TOPN);
    float*    topv  = (float*)(ws + O_TOPV);
    float*    normt = (float*)(ws + O_NORMT);

    hipMemsetAsync(mg, 0, 160000, stream);     // only mg needs a memset now
    k_pat<<<P_PAD, 64, 0, stream>>>(patterns, Ah, Al, mg, topn, topv, normt, pos);
    k_gemm<<<dim3(3, 4, 128), 256, 0, stream>>>(x, Ah, Al, length, pos);
    k_out<<<128, 256, 0, stream>>>(pos, topn, topv, mg, Wcls, normt, bcls, out);
}

// Round 4
// 146.406 us; speedup vs baseline: 1.7494x; 1.2847x over previous
//
#include <hip/hip_runtime.h>

#define N_NODE 200
#define T_LEN 360
#define T_POOL 350
#define P_PAT 400
#define P_PAD 512
#define NWIN 14
#define STRIDE_ 25
#define KPAD 224            // 7 stages x 32

// ---- workspace layout (bytes) ----
#define O_AH    0           // A hi, MFMA-fragment order: [7][8][4][64][8] bf16 = 229376
#define O_AL    229376      // A lo, same layout
#define O_MG    458752      // [200][200] i32 = 160000 (memset 0)
#define O_POS   618752      // [128][512][14] u32 = 3670016 (zeroed by k_pat)
#define O_TOPN  4288768
#define O_TOPV  4293568
#define O_NORMT 4298368

typedef unsigned short u16;
typedef __attribute__((ext_vector_type(8))) short bf16x8;
typedef __attribute__((ext_vector_type(4))) float f32x4;

__device__ __forceinline__ unsigned fkey(float f) {
    unsigned u = __float_as_uint(f);
    return (u & 0x80000000u) ? ~u : (u | 0x80000000u);
}
__device__ __forceinline__ u16 f2bf(float f) {          // RNE f32->bf16
    unsigned u = __float_as_uint(f);
    unsigned r = u + 0x7FFFu + ((u >> 16) & 1u);
    return (u16)(r >> 16);
}
__device__ __forceinline__ float bf2f(u16 h) { return __uint_as_float(((unsigned)h) << 16); }

// ---- pattern prep: normalize, top-3, norm term, maskgraph, frag-order bf16 split, pos zero ----
__global__ void k_pat(const float* __restrict__ pat, u16* __restrict__ Ah, u16* __restrict__ Al,
                      int* __restrict__ mg, int* __restrict__ topn_w,
                      float* __restrict__ topv_w, float* __restrict__ normt,
                      unsigned* __restrict__ pos)
{
    int p = blockIdx.x;               // 0..511
    int lane = threadIdx.x;
    bool pv = p < P_PAT;

    {   // zero pos: 917504 u32 = 512 blocks x 64 threads x 28
        int base = blockIdx.x * 64 + lane;
        #pragma unroll
        for (int i = 0; i < 28; ++i) pos[base + i * 32768] = 0u;
    }

    float sv[4], av[4];
    int nn[4];
    float ss = 0.f;
    #pragma unroll
    for (int j = 0; j < 4; ++j) {
        int n = lane + 64 * j;
        nn[j] = n;
        if (pv && n < N_NODE) { float v = pat[p * N_NODE + n]; sv[j] = v; av[j] = fabsf(v); ss += v * v; }
        else { sv[j] = 0.f; av[j] = -1.f; }
    }
    #pragma unroll
    for (int off = 32; off >= 1; off >>= 1) ss += __shfl_xor(ss, off);
    float rn = 1.0f / sqrtf(ss + 1e-9f);

    // fragment-order split write: idx = (((s*8+pb)*4+i)*64 + quad*16+lm)*8 + e
    int pb = p >> 6, ii = (p >> 4) & 3, plm = p & 15;
    #pragma unroll
    for (int j = 0; j < 4; ++j) {
        int n = nn[j];
        if (n < KPAD) {
            float v = (pv && n < N_NODE) ? sv[j] * rn : 0.f;
            u16 h = f2bf(v);
            u16 l = f2bf(v - bf2f(h));
            int s = n >> 5, c = n & 31, quad = c >> 3, e = c & 7;
            size_t idx = ((size_t)((s * 8 + pb) * 4 + ii) * 64 + quad * 16 + plm) * 8 + e;
            Ah[idx] = h; Al[idx] = l;
        }
    }
    if (!pv) return;

    int topn[3]; float topv[3];
    for (int r = 0; r < 3; ++r) {
        float bv = -2.f; int bi = 1 << 30;
        #pragma unroll
        for (int j = 0; j < 4; ++j)
            if (av[j] > bv || (av[j] == bv && nn[j] < bi)) { bv = av[j]; bi = nn[j]; }
        #pragma unroll
        for (int off = 32; off >= 1; off >>= 1) {
            float ov = __shfl_xor(bv, off); int oi = __shfl_xor(bi, off);
            if (ov > bv || (ov == bv && oi < bi)) { bv = ov; bi = oi; }
        }
        int jj = bi >> 6, src = bi & 63;
        float rawj = (jj == 0) ? sv[0] : (jj == 1) ? sv[1] : (jj == 2) ? sv[2] : sv[3];
        float raw = __shfl(rawj, src);
        topn[r] = bi; topv[r] = raw * rn;
        #pragma unroll
        for (int j = 0; j < 4; ++j) if (nn[j] == bi) av[j] = -1.f;
    }
    float fullnorm = sqrtf(ss) * rn;
    float topnorm = sqrtf(topv[0]*topv[0] + topv[1]*topv[1] + topv[2]*topv[2]);
    if (lane == 0) {
        float d = 1.0f - topnorm / fullnorm;
        normt[p] = d * d * (1.0f / 800.0f);
    }
    if (lane < 3) { topn_w[p * 3 + lane] = topn[lane]; topv_w[p * 3 + lane] = topv[lane]; }
    if (lane < 9) {
        int i = lane / 3, j = lane % 3;
        atomicAdd(&mg[topn[i] * N_NODE + topn[j]], 1);
    }
}

// ---- MFMA GEMM: A direct-from-global frags, X double-buffered LDS, 1 barrier/stage ----
#define RP 2064          // LDS X row pitch bytes (4 k-oct rows; even-t cells [0,1024), odd-t [1024,2048))
#define XLOFF 8256       // 4*RP : lo-plane offset
#define DBS 16512        // double-buffer stride (hi+lo)
#define SQOFF 16896      // ssq scratch (aliases dead buf1)
#define IVOFF 18944      // inv-norm per local t (128 f32)
__global__ __launch_bounds__(256, 3) void k_gemm(const float* __restrict__ x,
    const u16* __restrict__ AhF, const u16* __restrict__ AlF,
    const int* __restrict__ length, unsigned* __restrict__ pos)
{
    __shared__ __align__(16) char smem[33024];
    int tid = threadIdx.x;
    int b = blockIdx.z, p0 = blockIdx.y * 128, t0 = blockIdx.x * 128;
    int lane = tid & 63, wid = tid >> 6;
    int quad = lane >> 4, lm = lane & 15;
    int wp = wid >> 1, wt = wid & 1;
    const float* xb = x + (size_t)b * (N_NODE * T_LEN);

    f32x4 acc[4][4];
    #pragma unroll
    for (int i = 0; i < 4; ++i)
        #pragma unroll
        for (int j = 0; j < 4; ++j) acc[i][j] = (f32x4){0.f, 0.f, 0.f, 0.f};
    float ssq0 = 0.f, ssq1 = 0.f;

    // staging: wave wid = k-oct row, lane = t-pair
    int tg = t0 + 2 * lane;
    bool tok = tg < T_LEN;
    // fragment read base (parity-split t cells)
    int xfb = quad * RP + (lm & 1) * 1024 + (lm >> 1) * 16 + wt * 512;
    int pbq = blockIdx.y * 2 + wp;

    float2 xv[8];
    auto loadX = [&](int s) {
        int kb = s * 32 + wid * 8;
        #pragma unroll
        for (int e = 0; e < 8; ++e) {
            int k = kb + e;                                   // wave-uniform guard
            xv[e] = (tok && k < N_NODE) ? *(const float2*)(xb + k * T_LEN + tg)
                                        : make_float2(0.f, 0.f);
        }
    };
    auto cw = [&](int buf) {   // convert f32 -> hi/lo bf16, accumulate ssq, write LDS
        union { u16 us[8]; uint4 v; } H0, H1, L0, L1;
        #pragma unroll
        for (int e = 0; e < 8; ++e) {
            float f0 = xv[e].x, f1 = xv[e].y;
            ssq0 = fmaf(f0, f0, ssq0); ssq1 = fmaf(f1, f1, ssq1);
            u16 h = f2bf(f0); H0.us[e] = h; L0.us[e] = f2bf(f0 - bf2f(h));
            h = f2bf(f1);     H1.us[e] = h; L1.us[e] = f2bf(f1 - bf2f(h));
        }
        char* bp = smem + buf * DBS + wid * RP + lane * 16;
        *(uint4*)(bp)               = H0.v;   // even t
        *(uint4*)(bp + 1024)        = H1.v;   // odd t
        *(uint4*)(bp + XLOFF)        = L0.v;
        *(uint4*)(bp + XLOFF + 1024) = L1.v;
    };

    loadX(0); cw(0);
    bf16x8 ah[4], al[4], xh[4], xl[4];
    for (int s = 0; s < 7; ++s) {
        // A fragments straight from global (L2-resident, 459 KB total)
        const u16* Ab  = AhF + ((size_t)((s * 8 + pbq) * 4)) * 512 + lane * 8;
        const u16* Ab2 = AlF + ((size_t)((s * 8 + pbq) * 4)) * 512 + lane * 8;
        #pragma unroll
        for (int i = 0; i < 4; ++i) {
            ah[i] = *(const bf16x8*)(Ab  + i * 512);
            al[i] = *(const bf16x8*)(Ab2 + i * 512);
        }
        if (s < 6) loadX(s + 1);                 // prefetch next X while MFMA runs
        __syncthreads();                         // buf[s&1] writes visible
        const char* rb = smem + (s & 1) * DBS + xfb;
        #pragma unroll
        for (int j = 0; j < 4; ++j) {
            xh[j] = *(const bf16x8*)(rb + j * 128);
            xl[j] = *(const bf16x8*)(rb + XLOFF + j * 128);
        }
        // term-major: 16 independent accs between reuses (no dep chains)
        #pragma unroll
        for (int i = 0; i < 4; ++i)
            #pragma unroll
            for (int j = 0; j < 4; ++j)
                acc[i][j] = __builtin_amdgcn_mfma_f32_16x16x32_bf16(ah[i], xh[j], acc[i][j], 0, 0, 0);
        #pragma unroll
        for (int i = 0; i < 4; ++i)
            #pragma unroll
            for (int j = 0; j < 4; ++j)
                acc[i][j] = __builtin_amdgcn_mfma_f32_16x16x32_bf16(ah[i], xl[j], acc[i][j], 0, 0, 0);
        #pragma unroll
        for (int i = 0; i < 4; ++i)
            #pragma unroll
            for (int j = 0; j < 4; ++j)
                acc[i][j] = __builtin_amdgcn_mfma_f32_16x16x32_bf16(al[i], xh[j], acc[i][j], 0, 0, 0);
        if (s < 6) cw((s + 1) & 1);              // write other buffer; next barrier publishes
    }

    // frame-norm: reduce per-thread ssq (t-pair) over the 4 k-oct waves
    __syncthreads();
    *(float2*)&smem[SQOFF + tid * 8] = make_float2(ssq0, ssq1);
    __syncthreads();
    int sap = length[b] / STRIDE_;
    int tvalid = sap * STRIDE_;
    if (tid < 64) {
        float a0 = 0.f, a1 = 0.f;
        #pragma unroll
        for (int w2 = 0; w2 < 4; ++w2) {
            float2 v = *(float2*)&smem[SQOFF + (w2 * 64 + tid) * 8];
            a0 += v.x; a1 += v.y;
        }
        float rs = 1.0f / (float)sap;
        int ta = t0 + 2 * tid;
        ((float*)&smem[IVOFF])[2 * tid]     = (ta     < tvalid) ? rs / sqrtf(a0 + 1e-9f) : 0.f;
        ((float*)&smem[IVOFF])[2 * tid + 1] = (ta + 1 < tvalid) ? rs / sqrtf(a1 + 1e-9f) : 0.f;
    }
    __syncthreads();
    float invv[4];
    #pragma unroll
    for (int j = 0; j < 4; ++j) invv[j] = ((float*)&smem[IVOFF])[wt * 64 + j * 16 + lm];

    // epilogue: 4 rounds x 32 p-rows (Ss aliases dead X buffers)
    float* Ss = (float*)smem;
    int wbase = t0 / STRIDE_;
    int tmax = min(t0 + 128, T_POOL);
    for (int rr = 0; rr < 4; ++rr) {
        __syncthreads();
        if (wp == (rr >> 1)) {
            #pragma unroll
            for (int i2 = 0; i2 < 2; ++i2) {
                int i = (rr & 1) * 2 + i2;
                #pragma unroll
                for (int j = 0; j < 4; ++j) {
                    int col = wt * 64 + j * 16 + lm;
                    #pragma unroll
                    for (int r = 0; r < 4; ++r)
                        Ss[(i2 * 16 + quad * 4 + r) * 132 + col] = acc[i][j][r] * invv[j];
                }
            }
        }
        __syncthreads();
        int sidx = tid & 7, pl = tid >> 3;       // 32 p-rows x 8 windows = 256 threads
        int w = wbase + sidx;
        int tlo = max(w * STRIDE_, t0), thi = min(w * STRIDE_ + STRIDE_, tmax);
        if (w < NWIN && tlo < thi) {
            float m = -3.4e38f;
            for (int t = tlo; t < thi; ++t) m = fmaxf(m, Ss[pl * 132 + (t - t0)]);
            atomicMax(&pos[((size_t)b * P_PAD + p0 + rr * 32 + pl) * NWIN + w], fkey(m));
        }
    }
}

// ---- final: coef inline, fs reduce, norm reduce ----
__global__ void k_out(const unsigned* __restrict__ pos, const int* __restrict__ topn_w,
                      const float* __restrict__ topv_w, const int* __restrict__ mg,
                      const float* __restrict__ W, const float* __restrict__ normt,
                      const float* __restrict__ bcls, float* __restrict__ out)
{
    __shared__ float cf0[P_PAT], cf1[P_PAT];
    __shared__ float sh[512];
    int b = blockIdx.x, tid = threadIdx.x;
    for (int p = tid; p < P_PAT; p += 256) {
        int tn[3]; float tv[3];
        #pragma unroll
        for (int i = 0; i < 3; ++i) { tn[i] = topn_w[p * 3 + i]; tv[i] = topv_w[p * 3 + i]; }
        float c0 = 0.f, c1 = 0.f;
        #pragma unroll
        for (int i = 0; i < 3; ++i)
            #pragma unroll
            for (int j = 0; j < 3; ++j) {
                int nm = tn[i] * N_NODE + tn[j];
                float f = tv[i] * tv[j] / ((float)mg[nm] + 1e-9f);
                c0 += f * W[nm * 2 + 0];
                c1 += f * W[nm * 2 + 1];
            }
        cf0[p] = c0; cf1[p] = c1;
    }
    __syncthreads();
    float s0 = 0.f, s1 = 0.f;
    for (int p = tid; p < P_PAT; p += 256) {
        const unsigned* pp = pos + ((size_t)b * P_PAD + p) * NWIN;
        float fs = 0.f;
        #pragma unroll
        for (int w = 0; w < NWIN; ++w) {
            unsigned k = pp[w];
            unsigned u = (k & 0x80000000u) ? (k ^ 0x80000000u) : ~k;
            fs += __uint_as_float(u);
        }
        s0 += fs * cf0[p];
        s1 += fs * cf1[p];
    }
    sh[tid] = s0; sh[256 + tid] = s1;
    __syncthreads();
    for (int o = 128; o > 0; o >>= 1) {
        if (tid < o) { sh[tid] += sh[tid + o]; sh[256 + tid] += sh[256 + tid + o]; }
        __syncthreads();
    }
    if (tid == 0) {
        out[b * 2 + 0] = sh[0]   + bcls[0];
        out[b * 2 + 1] = sh[256] + bcls[1];
    }
    if (b == 0) {
        __syncthreads();
        float ns = 0.f;
        for (int i = tid; i < P_PAT; i += 256) ns += normt[i];
        sh[tid] = ns;
        __syncthreads();
        for (int o = 128; o > 0; o >>= 1) {
            if (tid < o) sh[tid] += sh[tid + o];
            __syncthreads();
        }
        if (tid == 0) { out[256] = sh[0]; out[257] = 0.f; }
    }
}

extern "C" void kernel_launch(void* const* d_in, const int* in_sizes, int n_in,
                              void* d_out, int out_size, void* d_ws, size_t ws_size,
                              hipStream_t stream) {
    (void)in_sizes; (void)n_in; (void)out_size; (void)ws_size;
    const float* x        = (const float*)d_in[0];
    const int*   length   = (const int*)d_in[1];
    const float* patterns = (const float*)d_in[2];
    const float* Wcls     = (const float*)d_in[3];
    const float* bcls     = (const float*)d_in[4];
    float* out = (float*)d_out;
    char* ws = (char*)d_ws;

    u16*      Ah    = (u16*)(ws + O_AH);
    u16*      Al    = (u16*)(ws + O_AL);
    int*      mg    = (int*)(ws + O_MG);
    unsigned* pos   = (unsigned*)(ws + O_POS);
    int*      topn  = (int*)(ws + O_TOPN);
    float*    topv  = (float*)(ws + O_TOPV);
    float*    normt = (float*)(ws + O_NORMT);

    hipMemsetAsync(mg, 0, 160000, stream);
    k_pat<<<P_PAD, 64, 0, stream>>>(patterns, Ah, Al, mg, topn, topv, normt, pos);
    k_gemm<<<dim3(3, 4, 128), 256, 0, stream>>>(x, Ah, Al, length, pos);
    k_out<<<128, 256, 0, stream>>>(pos, topn, topv, mg, Wcls, normt, bcls, out);
}